// Round 6
// baseline (178.897 us; speedup 1.0000x reference)
//
#include <hip/hip_runtime.h>
#include <math.h>

#define HW    9216
#define KJ    17
#define BATCH 128
#define TOPK  8
#define ROWS  (BATCH * KJ)           // 2176
#define PARTS 3                      // blocks per row
#define F4_PER_PART 768              // 2304 float4 per row / 3
#define CHUNKS 12                    // 64-float4 (1 KB) DMA chunks per input per block

// R4 post-mortem: VGPR-return loads plateau at ~3 TB/s logical regardless of
// structure (chain depth, ILP, occupancy, cache state) -> the L1/TA queue for
// VGPR-return loads is shallow (~212 cy per 1KB wave-load per CU). m97's GEMM
// sustained ~4x more per-CU read BW through global_load_lds DMA. So: stage
// through LDS. Each block DMAs 24KB (12 chunks x 2 inputs, width=16, zero
// VGPR results, all outstanding), drains once at __syncthreads, reduces from
// LDS. 6 blocks/CU resident -> ~144KB in flight per CU.
__global__ __launch_bounds__(256) void sq_partial_lds(
    const float* __restrict__ outp, const float* __restrict__ tgt,
    float* __restrict__ pj_parts)
{
    __shared__ float4 so[F4_PER_PART];   // 12 KB
    __shared__ float4 st[F4_PER_PART];   // 12 KB

    const int tid  = threadIdx.x;
    const int wave = tid >> 6;
    const int lane = tid & 63;
    const int blk  = blockIdx.x;                       // row*3 + part
    const size_t base = (size_t)blk * F4_PER_PART;     // flat float4 offset

    const float4* o4 = (const float4*)outp + base;
    const float4* t4 = (const float4*)tgt  + base;

    // DMA staging: wave w issues chunks w, w+4, w+8 for each input.
    // LDS dest = wave-uniform base + lane*16 (HW rule) -> contiguous chunk.
#pragma unroll
    for (int c = wave; c < CHUNKS; c += 4) {
        __builtin_amdgcn_global_load_lds(
            (const __attribute__((address_space(1))) void*)(o4 + c * 64 + lane),
            (__attribute__((address_space(3))) void*)&so[c * 64], 16, 0, 0);
        __builtin_amdgcn_global_load_lds(
            (const __attribute__((address_space(1))) void*)(t4 + c * 64 + lane),
            (__attribute__((address_space(3))) void*)&st[c * 64], 16, 0, 0);
    }
    __syncthreads();   // drains vmcnt for the DMA + barrier

    float ss = 0.f;
#pragma unroll
    for (int j = 0; j < 3; ++j) {
        float4 ov = so[tid + j * 256];
        float4 tv = st[tid + j * 256];
        float d0 = ov.x - tv.x;
        float d1 = ov.y - tv.y;
        float d2 = ov.z - tv.z;
        float d3 = ov.w - tv.w;
        ss += d0 * d0 + d1 * d1 + d2 * d2 + d3 * d3;
    }

    // wave64 shuffle reduce
#pragma unroll
    for (int off = 32; off > 0; off >>= 1)
        ss += __shfl_down(ss, off, 64);

    __shared__ float smem[4];
    if (lane == 0) smem[wave] = ss;
    __syncthreads();
    if (tid == 0)
        pj_parts[blk] = smem[0] + smem[1] + smem[2] + smem[3];  // direct store, no atomics
}

// Kernel 2: sum 3 partials per row, scale by w^2/HW, per-sample top-8-of-17,
// mean over batch. 1 block, 128 threads (one sample per thread).
__global__ __launch_bounds__(128) void ohkm_reduce(
    const float* __restrict__ pj_parts, const float* __restrict__ tw,
    float* __restrict__ result)
{
    const int b = threadIdx.x;   // 0..127
    float v[KJ];
#pragma unroll
    for (int k = 0; k < KJ; ++k) {
        const int r = b * KJ + k;
        float s = pj_parts[r * PARTS] + pj_parts[r * PARTS + 1] + pj_parts[r * PARTS + 2];
        float w = tw[r];
        v[k] = s * w * w * (1.0f / (float)HW);
    }

    float s = 0.f;
#pragma unroll
    for (int t = 0; t < TOPK; ++t) {
        float m = v[0];
#pragma unroll
        for (int k = 1; k < KJ; ++k) m = fmaxf(m, v[k]);
        s += m;
        // remove exactly the FIRST element equal to m (tie-safe top_k)
        bool removed = false;
#pragma unroll
        for (int k = 0; k < KJ; ++k) {
            bool hit = (!removed) && (v[k] == m);
            v[k] = hit ? -INFINITY : v[k];
            removed = removed || hit;
        }
    }

    // 128 threads = 2 waves
#pragma unroll
    for (int off = 32; off > 0; off >>= 1)
        s += __shfl_down(s, off, 64);

    __shared__ float smem[2];
    if ((b & 63) == 0) smem[b >> 6] = s;
    __syncthreads();
    if (b == 0)
        result[0] = (smem[0] + smem[1]) * (1.0f / (float)(BATCH * TOPK));
}

extern "C" void kernel_launch(void* const* d_in, const int* in_sizes, int n_in,
                              void* d_out, int out_size, void* d_ws, size_t ws_size,
                              hipStream_t stream) {
    const float* outp = (const float*)d_in[0];   // [128,17,96,96]
    const float* tgt  = (const float*)d_in[1];   // [128,17,96,96]
    const float* tw   = (const float*)d_in[2];   // [128,17,1]
    float* result   = (float*)d_out;             // scalar
    float* pj_parts = (float*)d_ws;              // [2176*3] unweighted partial sums

    sq_partial_lds<<<ROWS * PARTS, 256, 0, stream>>>(outp, tgt, pj_parts);
    ohkm_reduce<<<1, 128, 0, stream>>>(pj_parts, tw, result);
}